// Round 5
// baseline (308.133 us; speedup 1.0000x reference)
//
#include <hip/hip_runtime.h>
#include <stdint.h>

// LSTM autoencoder B=32768 T=30 I=4 H=64 L=32, fp32 in/out.
// v18 = OCCUPANCY UNPIN. v14-v17 post-mortem: VALU-busy TIME is invariant
// (~142us) across all restructurings; duration differences are idle-issue
// on top of it. At 16 batches/wave the wave count is structurally pinned at
// 2048 = 2 waves/SIMD, and ~40% of issue slots are unfillable stalls.
// v18 splits each 16-batch group across TWO cooperating waves by UNITS
// (enc1/dec1: unit-quarters {2wh,2wh+1}; enc2: half wh; dec2: wh==1),
// keeping MFMA tiles full-width -> total MFMA unchanged, per-wave VALU
// halves, waves double to 4096 = 4 waves/SIMD. Halves exchange h via the
// group LDS images with 2 __syncthreads per step (reads||alpha||writes||beta).
// 8-wave blocks, LDS trimmed to 80448B -> 2 blocks/CU (barrier waits of one
// block covered by the other). VGPR capped at 128 via waves_per_eu(4).
//  - h1/h3 and h2 single-buffered (2-barrier pattern makes dbuf redundant).
//  - gbuf + bufH4 alias the latent region in dec (latent hoisted to regs).
//  - reg hoists trimmed to w1a (8 tiles, 32 VGPR; carries the bias-in-k-slot
//    trick). Biases/Wih3/W4 read from LDS in-loop (TLP now covers latency).
// Math/quantization identical: 1-term bf16 h, 2-term x + 2-term bias,
// log2e folded into weights, unitH = 5 exp2 + 2 rcp. absmax 9.77e-4.
// Layouts (HW-verified): C/D col=lane&15(batch), row=(lane>>4)*4+reg(unit)
// [m89]; A/B m|n=lane&15, k=(lane>>4)*8+j [m120].

typedef unsigned short u16;
typedef unsigned int u32;
typedef __attribute__((ext_vector_type(8))) short bf16x8;
typedef __attribute__((ext_vector_type(4))) float f32x4;
typedef __attribute__((ext_vector_type(4))) u32 u32x4;
typedef __attribute__((ext_vector_type(2))) u32 u32x2;

#define BATCH 32768
#define TT 30
#define IN 4
#define WAVES 8
#define BLOCKT (WAVES * 64)   // 512
#define MB 16                 // batches per group
#define NGRP 4                // groups per block (2 waves each)
#define BPB (NGRP * MB)       // 64 -> grid 512, 2 blocks/CU

#define LOG2E 1.4426950408889634f
#define LOG2E2 2.8853900817779268f

// ---- LDS word offsets ----
// enc weights (0..16383)
#define O_WHH1 0        // 8192
#define O_W1C  8192     // 2048 (256 rows x 16 u16: whi4|wlo4|bhi|blo|0x6)
#define O_WIH2 10240    // 4096
#define O_WHH2 14336    // 2048 -> 16384
// dec weights (same region, restaged)
#define O_WHH3 0        // 8192
#define O_WIH3 8192     // 4096
#define O_WIH4 12288    // 512
#define O_W4HHF 12800   // 64 -> 12864
// biases (survive restage)
#define O_B2F 16384     // 128
#define O_B3F 16512     // 256
#define O_B4F 16768     // 16
#define O_BUFS 16784
// per-group: h1/h3 512w | h2/latent 256w (gbuf aliases in dec) | h4 64w
#define PBUF 832
#define SMEM_WORDS (O_BUFS + NGRP * PBUF)   // 20112
#define SMEM_BYTES (SMEM_WORDS * 4)         // 80448 -> 2 blocks/CU (160896<=163840)

#define WB() __builtin_amdgcn_wave_barrier()
// arg order: A = weight frag, B = data frag.
#define MFMA(a, b, c) __builtin_amdgcn_mfma_f32_16x16x32_bf16((a), (b), (c), 0, 0, 0)

__device__ __forceinline__ u16 f2bf(float f) {   // RNE fp32->bf16 (staging)
    u32 u = __float_as_uint(f);
    u += 0x7fffu + ((u >> 16) & 1u);
    return (u16)(u >> 16);
}
__device__ __forceinline__ float bf2f(u16 v) { return __uint_as_float(((u32)v) << 16); }

__device__ __forceinline__ u32 cvtpk2(float a, float b) {   // packed RNE fp32x2->bf16x2
    u32 d;
    asm("v_cvt_pk_bf16_f32 %0, %1, %2" : "=v"(d) : "v"(a), "v"(b));
    return d;
}

// Fused LSTM cell update. Inputs pre-scaled (i,f,o by log2e; g by 2*log2e).
__device__ __forceinline__ float unitH(float yi, float yf, float yg, float yo, float& c) {
    const float ei = __builtin_amdgcn_exp2f(-yi);
    const float ef = __builtin_amdgcn_exp2f(-yf);
    const float eg = __builtin_amdgcn_exp2f(yg);
    const float eo = __builtin_amdgcn_exp2f(-yo);
    const float Z = (1.f + ei) * (1.f + eg);
    const float X = 1.f + ef;
    const float num = fmaf(eg - 1.f, X, c * Z);
    c = num * __builtin_amdgcn_rcpf(X * Z);
    const float ec = __builtin_amdgcn_exp2f(c * LOG2E2);
    return (ec - 1.f) * __builtin_amdgcn_rcpf((1.f + eo) * (1.f + ec));
}

// Stage fp32 W[N][K] -> bf16 hi, fragment order, rows pre-scaled by gate factor.
template <int KT, int GS>
__device__ __forceinline__ void stageBh(u16* hi, const float* src, int N, int tid) {
    const int K = KT * 32;
    const int total = N * K;
    for (int idx = tid; idx < total; idx += BLOCKT) {
        const int j = idx & 7;
        const int l = (idx >> 3) & 63;
        const int pr = idx >> 9;
        const int kt = pr & (KT - 1);
        const int nt = pr / KT;
        const int n = (nt << 4) | (l & 15);
        const int k = (kt << 5) + ((l >> 4) << 3) + j;
        const float s = (((n >> GS) & 3) == 2) ? LOG2E2 : LOG2E;
        hi[idx] = f2bf(src[n * K + k] * s);
    }
}

__global__ __launch_bounds__(BLOCKT)
__attribute__((amdgpu_waves_per_eu(4)))
void lstm_ae(
    const float* __restrict__ x,
    const float* __restrict__ w1ih, const float* __restrict__ w1hh,
    const float* __restrict__ b1i, const float* __restrict__ b1h,
    const float* __restrict__ w2ih, const float* __restrict__ w2hh,
    const float* __restrict__ b2i, const float* __restrict__ b2h,
    const float* __restrict__ w3ih, const float* __restrict__ w3hh,
    const float* __restrict__ b3i, const float* __restrict__ b3h,
    const float* __restrict__ w4ih, const float* __restrict__ w4hh,
    const float* __restrict__ b4i, const float* __restrict__ b4h,
    float* __restrict__ out) {
    extern __shared__ float smem[];
    float* W = smem;

    const int tid = threadIdx.x;
    const int wave = tid >> 6, lane = tid & 63;
    const int wg = wave >> 1, wh = wave & 1;   // group, half
    const int col = lane & 15, quad = lane >> 4;
    const int q0 = wh << 1;                    // unit-quarter base for this half

    float* pb = smem + O_BUFS + wg * PBUF;
    u16* h1b = (u16*)pb;             // 1024 u16: h1 (enc) / h3 (dec), single buf
    u16* h2b = (u16*)(pb + 512);     // 512 u16: h2 / latent (enc)
    float* gbuf = pb + 512;          // 256 f: dec2 gate transpose (aliases h2b)
    float* bufH4 = pb + 768;         // 64 f: dec2 h feedback

    const int b0w = blockIdx.x * BPB + wg * MB;
    const int hbase = (col << 3) + ((quad & 1) << 2) + ((quad >> 1) << 7);

    // ---------------- stage ENCODER weights + biases ----------------
    stageBh<2, 6>((u16*)(W + O_WHH1), w1hh, 256, tid);
    stageBh<2, 5>((u16*)(W + O_WIH2), w2ih, 128, tid);
    stageBh<1, 5>((u16*)(W + O_WHH2), w2hh, 128, tid);
    {   // W1C rows (16 u16): [whi0-3 | wlo0-3 | bhi | blo | 0 x6]
        u16* C = (u16*)(W + O_W1C);
        for (int idx = tid; idx < 256 * 16; idx += BLOCKT) {
            const int n = idx >> 4, j = idx & 15;
            const float sc = ((n >> 6) == 2) ? LOG2E2 : LOG2E;
            u16 v = 0;
            if (j < 4) {
                v = f2bf(w1ih[n * 4 + j] * sc);
            } else if (j < 8) {
                const float w = w1ih[n * 4 + (j - 4)] * sc;
                v = f2bf(w - bf2f(f2bf(w)));
            } else if (j == 8) {
                v = f2bf((b1i[n] + b1h[n]) * sc);
            } else if (j == 9) {
                const float b = (b1i[n] + b1h[n]) * sc;
                v = f2bf(b - bf2f(f2bf(b)));
            }
            C[idx] = v;
        }
    }
    float* b2f = W + O_B2F;
    float* b3f = W + O_B3F;
    float* b4f = W + O_B4F;
    for (int i = tid; i < 128; i += BLOCKT)
        b2f[i] = (b2i[i] + b2h[i]) * (((i >> 5) == 2) ? LOG2E2 : LOG2E);
    for (int i = tid; i < 256; i += BLOCKT)
        b3f[i] = (b3i[i] + b3h[i]) * (((i >> 6) == 2) ? LOG2E2 : LOG2E);
    for (int i = tid; i < 16; i += BLOCKT)
        b4f[i] = (b4i[i] + b4h[i]) * (((i >> 2) == 2) ? LOG2E2 : LOG2E);
    {   // zero h2 + h4 (h1 needs no zero: prologue writes full image)
        u32* z = (u32*)pb;
        if (wh == 0) {
            for (int i = lane; i < 256; i += 64) z[512 + i] = 0u;
        } else {
            bufH4[lane] = 0.f;
        }
    }
    __syncthreads();

    const u16* Whh1hi = (const u16*)(W + O_WHH1);
    const u16* Wih2hi = (const u16*)(W + O_WIH2);
    const u16* Whh2hi = (const u16*)(W + O_WHH2);

    // ---- hoist this half's enc1 fold A-frags (8 tiles, 32 VGPR) ----
    //   q0l=[whi,whi](k0-7: x hi|lo), q1=[wlo,wlo](k8-15), q2=[bhi,blo,0..](k16-17: 1.0)
    bf16x8 w1a[2][4];
    {
        const u16* Cx = (const u16*)(W + O_W1C);
#pragma unroll
        for (int ql = 0; ql < 2; ++ql)
#pragma unroll
            for (int i = 0; i < 4; ++i) {
                const int nt = i * 4 + q0 + ql;
                const u16* row = Cx + (((nt << 4) | col) << 4);
                u32x4 v = {0u, 0u, 0u, 0u};
                if (quad == 0) {
                    const u32x2 p = *reinterpret_cast<const u32x2*>(row);
                    v.x = p.x; v.y = p.y; v.z = p.x; v.w = p.y;
                } else if (quad == 1) {
                    const u32x2 p = *reinterpret_cast<const u32x2*>(row + 4);
                    v.x = p.x; v.y = p.y; v.z = p.x; v.w = p.y;
                } else if (quad == 2) {
                    v.x = *reinterpret_cast<const u32*>(row + 8);
                }
                w1a[ql][i] = __builtin_bit_cast(bf16x8, v);
            }
    }

    // ================= encoder =================
    float c1[2][4];   // this half's unit-quarters
    float c2v[4];     // this half's enc2 quarter
#pragma unroll
    for (int ql = 0; ql < 2; ++ql)
#pragma unroll
        for (int r = 0; r < 4; ++r) c1[ql][r] = 0.f;
#pragma unroll
    for (int r = 0; r < 4; ++r) c2v[r] = 0.f;

    const f32x4 zf = {0.f, 0.f, 0.f, 0.f};
    float4 xcur = *reinterpret_cast<const float4*>(x + ((size_t)(b0w + col) * TT + 0) * IN);

    // x B-frag: quad0 [xhi,xlo], quad1 [xhi,0], quad2 [1.0 1.0 (bias slots)], quad3 0
    auto buildX = [&](const float4 xc) -> bf16x8 {
        const u32 hi01 = cvtpk2(xc.x, xc.y);
        const u32 hi23 = cvtpk2(xc.z, xc.w);
        const float r0 = xc.x - __uint_as_float(hi01 << 16);
        const float r1 = xc.y - __uint_as_float(hi01 & 0xffff0000u);
        const float r2 = xc.z - __uint_as_float(hi23 << 16);
        const float r3 = xc.w - __uint_as_float(hi23 & 0xffff0000u);
        const u32 lo01 = cvtpk2(r0, r1);
        const u32 lo23 = cvtpk2(r2, r3);
        u32x4 xv;
        xv.x = (quad <= 1) ? hi01 : ((quad == 2) ? 0x3F803F80u : 0u);
        xv.y = (quad <= 1) ? hi23 : 0u;
        xv.z = (quad == 0) ? lo01 : 0u;
        xv.w = (quad == 0) ? lo23 : 0u;
        return __builtin_bit_cast(bf16x8, xv);
    };

    // enc1 for this half: 24 MFMA + 8 unitH, writes own h1 half
    auto enc1_half = [&](const bf16x8 a1x, const bf16x8 ah0, const bf16x8 ah1) {
#pragma unroll
        for (int ql = 0; ql < 2; ++ql) {
            f32x4 acc[4];
#pragma unroll
            for (int i = 0; i < 4; ++i) {
                const int nt = i * 4 + q0 + ql;
                const bf16x8 bh0 = *reinterpret_cast<const bf16x8*>(Whh1hi + ((nt * 2 + 0) * 64 + lane) * 8);
                const bf16x8 bh1 = *reinterpret_cast<const bf16x8*>(Whh1hi + ((nt * 2 + 1) * 64 + lane) * 8);
                f32x4 a = MFMA(w1a[ql][i], a1x, zf);
                a = MFMA(bh0, ah0, a);
                a = MFMA(bh1, ah1, a);
                acc[i] = a;
            }
            const float h0 = unitH(acc[0][0], acc[1][0], acc[2][0], acc[3][0], c1[ql][0]);
            const float h1 = unitH(acc[0][1], acc[1][1], acc[2][1], acc[3][1], c1[ql][1]);
            const float h2 = unitH(acc[0][2], acc[1][2], acc[2][2], acc[3][2], c1[ql][2]);
            const float h3 = unitH(acc[0][3], acc[1][3], acc[2][3], acc[3][3], c1[ql][3]);
            u32x2 wv;
            wv.x = cvtpk2(h0, h1);
            wv.y = cvtpk2(h2, h3);
            *reinterpret_cast<u32x2*>(h1b + hbase + (wh << 9) + (ql << 8)) = wv;
        }
    };
    // enc2 for this half: 12 MFMA + 4 unitH, writes own h2 half
    auto enc2_half = [&](const bf16x8 ah0, const bf16x8 ah1, const bf16x8 a2h) {
        f32x4 g4[4];
#pragma unroll
        for (int g = 0; g < 4; ++g) {
            const int nt = g * 2 + wh;
            const bf16x8 bh0 = *reinterpret_cast<const bf16x8*>(Wih2hi + ((nt * 2 + 0) * 64 + lane) * 8);
            const bf16x8 bh1 = *reinterpret_cast<const bf16x8*>(Wih2hi + ((nt * 2 + 1) * 64 + lane) * 8);
            const bf16x8 ch = *reinterpret_cast<const bf16x8*>(Whh2hi + (nt * 64 + lane) * 8);
            f32x4 a = *reinterpret_cast<const f32x4*>(b2f + nt * 16 + (quad << 2));
            a = MFMA(bh0, ah0, a);
            a = MFMA(bh1, ah1, a);
            a = MFMA(ch, a2h, a);
            g4[g] = a;
        }
        const float h0 = unitH(g4[0][0], g4[1][0], g4[2][0], g4[3][0], c2v[0]);
        const float h1 = unitH(g4[0][1], g4[1][1], g4[2][1], g4[3][1], c2v[1]);
        const float h2 = unitH(g4[0][2], g4[1][2], g4[2][2], g4[3][2], c2v[2]);
        const float h3 = unitH(g4[0][3], g4[1][3], g4[2][3], g4[3][3], c2v[3]);
        u32x2 wv;
        wv.x = cvtpk2(h0, h1);
        wv.y = cvtpk2(h2, h3);
        *reinterpret_cast<u32x2*>(h2b + hbase + (wh << 8)) = wv;
    };

    {   // prologue: enc1[0] with h1[-1]=0
        const bf16x8 z8 = {};
        const bf16x8 a1x = buildX(xcur);
        xcur = *reinterpret_cast<const float4*>(x + ((size_t)(b0w + col) * TT + 1) * IN);
        enc1_half(a1x, z8, z8);
    }
    __syncthreads();

    for (int t = 0; t < TT - 1; ++t) {
        // reads (before alpha)
        const bf16x8 ah0 = *reinterpret_cast<const bf16x8*>(h1b + lane * 8);        // h1[t]
        const bf16x8 ah1 = *reinterpret_cast<const bf16x8*>(h1b + (64 + lane) * 8);
        const bf16x8 a2h = *reinterpret_cast<const bf16x8*>(h2b + lane * 8);        // h2[t-1]
        __syncthreads();   // alpha: all reads done before any writes
        enc2_half(ah0, ah1, a2h);                    // writes h2[t] half
        const bf16x8 a1x = buildX(xcur);
        {
            const int tn = (t + 2 < TT) ? t + 2 : TT - 1;
            xcur = *reinterpret_cast<const float4*>(x + ((size_t)(b0w + col) * TT + tn) * IN);
        }
        enc1_half(a1x, ah0, ah1);                    // writes h1[t+1] half
        __syncthreads();   // beta: writes visible for next step's reads
    }
    {   // epilogue: enc2[TT-1] -> latent
        const bf16x8 ah0 = *reinterpret_cast<const bf16x8*>(h1b + lane * 8);
        const bf16x8 ah1 = *reinterpret_cast<const bf16x8*>(h1b + (64 + lane) * 8);
        const bf16x8 a2h = *reinterpret_cast<const bf16x8*>(h2b + lane * 8);
        __syncthreads();
        enc2_half(ah0, ah1, a2h);
    }
    __syncthreads();
    const bf16x8 aLh = *reinterpret_cast<const bf16x8*>(h2b + lane * 8);   // latent -> regs

    // ---------------- re-stage DECODER weights ----------------
    stageBh<2, 6>((u16*)(W + O_WHH3), w3hh, 256, tid);
    stageBh<1, 6>((u16*)(W + O_WIH3), w3ih, 256, tid);
    stageBh<2, 2>((u16*)(W + O_WIH4), w4ih, 16, tid);
    for (int i = tid; i < 64; i += BLOCKT)
        W[O_W4HHF + i] = w4hh[i] * ((((i >> 4) & 3) == 2) ? LOG2E2 : LOG2E);

    float c3[2][4];
#pragma unroll
    for (int ql = 0; ql < 2; ++ql)
#pragma unroll
        for (int r = 0; r < 4; ++r) c3[ql][r] = 0.f;
    float c4 = 0.f;
    const int u4 = lane & 3, mb = lane >> 2;
    __syncthreads();   // dec weights visible; enc reads all done before restage started

    const u16* Whh3hi = (const u16*)(W + O_WHH3);
    const u16* Wih3hi = (const u16*)(W + O_WIH3);
    const u16* Wih4hi = (const u16*)(W + O_WIH4);
    const float* W4hhF = W + O_W4HHF;
    const f32x4 bias4v = *reinterpret_cast<const f32x4*>(b4f + (quad << 2));

    // dec1 for this half: 24 MFMA + 8 unitH, writes own h3 half
    auto dec1_half = [&](const bf16x8 ah0, const bf16x8 ah1) {
#pragma unroll
        for (int ql = 0; ql < 2; ++ql) {
            f32x4 acc[4];
#pragma unroll
            for (int i = 0; i < 4; ++i) {
                const int nt = i * 4 + q0 + ql;
                const bf16x8 bL = *reinterpret_cast<const bf16x8*>(Wih3hi + (nt * 64 + lane) * 8);
                const bf16x8 bh0 = *reinterpret_cast<const bf16x8*>(Whh3hi + ((nt * 2 + 0) * 64 + lane) * 8);
                const bf16x8 bh1 = *reinterpret_cast<const bf16x8*>(Whh3hi + ((nt * 2 + 1) * 64 + lane) * 8);
                f32x4 a = *reinterpret_cast<const f32x4*>(b3f + nt * 16 + (quad << 2));
                a = MFMA(bL, aLh, a);
                a = MFMA(bh0, ah0, a);
                a = MFMA(bh1, ah1, a);
                acc[i] = a;
            }
            const float h0 = unitH(acc[0][0], acc[1][0], acc[2][0], acc[3][0], c3[ql][0]);
            const float h1 = unitH(acc[0][1], acc[1][1], acc[2][1], acc[3][1], c3[ql][1]);
            const float h2 = unitH(acc[0][2], acc[1][2], acc[2][2], acc[3][2], c3[ql][2]);
            const float h3 = unitH(acc[0][3], acc[1][3], acc[2][3], acc[3][3], c3[ql][3]);
            u32x2 wv;
            wv.x = cvtpk2(h0, h1);
            wv.y = cvtpk2(h2, h3);
            *reinterpret_cast<u32x2*>(h1b + hbase + (wh << 9) + (ql << 8)) = wv;
        }
    };
    // dec2 (wh==1 only): 2 MFMA + transpose + 1 unitH + store
    auto dec2_step = [&](const bf16x8 ah0, const bf16x8 ah1, const float4 hv, int t) {
        f32x4 acc4 = bias4v;
#pragma unroll
        for (int r = 0; r < 4; ++r) {
            const float4 w4 = *reinterpret_cast<const float4*>(W4hhF + ((quad * 4 + r) << 2));
            float sa = acc4[r];
            sa = fmaf(w4.x, hv.x, sa);
            sa = fmaf(w4.y, hv.y, sa);
            sa = fmaf(w4.z, hv.z, sa);
            sa = fmaf(w4.w, hv.w, sa);
            acc4[r] = sa;
        }
        const bf16x8 w4f0 = *reinterpret_cast<const bf16x8*>(Wih4hi + (0 * 64 + lane) * 8);
        const bf16x8 w4f1 = *reinterpret_cast<const bf16x8*>(Wih4hi + (1 * 64 + lane) * 8);
        acc4 = MFMA(w4f0, ah0, acc4);
        acc4 = MFMA(w4f1, ah1, acc4);
        WB();
        *reinterpret_cast<f32x4*>(gbuf + (col << 4) + (quad << 2)) = acc4;   // wave-local
        WB();
        const float yi = gbuf[mb * 16 + u4];
        const float yf = gbuf[mb * 16 + 4 + u4];
        const float yg = gbuf[mb * 16 + 8 + u4];
        const float yo = gbuf[mb * 16 + 12 + u4];
        const float h = unitH(yi, yf, yg, yo, c4);
        out[((size_t)(b0w + mb) * TT + t) * IN + u4] = h;
        bufH4[mb * 4 + u4] = h;
    };

    {   // prologue: dec1[0] with h3[-1]=0
        const bf16x8 z8 = {};
        dec1_half(z8, z8);
    }
    __syncthreads();

    for (int t = 0; t < TT - 1; ++t) {
        const bf16x8 ah0 = *reinterpret_cast<const bf16x8*>(h1b + lane * 8);        // h3[t]
        const bf16x8 ah1 = *reinterpret_cast<const bf16x8*>(h1b + (64 + lane) * 8);
        float4 hv = {0.f, 0.f, 0.f, 0.f};
        if (wh) hv = *reinterpret_cast<const float4*>(bufH4 + (col << 2));          // h4[t-1]
        __syncthreads();   // alpha
        if (wh) dec2_step(ah0, ah1, hv, t);
        dec1_half(ah0, ah1);                         // writes h3[t+1] half
        __syncthreads();   // beta
    }
    {   // epilogue: dec2[TT-1]
        const bf16x8 ah0 = *reinterpret_cast<const bf16x8*>(h1b + lane * 8);
        const bf16x8 ah1 = *reinterpret_cast<const bf16x8*>(h1b + (64 + lane) * 8);
        if (wh) {
            const float4 hv = *reinterpret_cast<const float4*>(bufH4 + (col << 2));
            dec2_step(ah0, ah1, hv, TT - 1);
        }
    }
}

extern "C" void kernel_launch(void* const* d_in, const int* in_sizes, int n_in,
                              void* d_out, int out_size, void* d_ws, size_t ws_size,
                              hipStream_t stream) {
    (void)in_sizes; (void)n_in; (void)d_ws; (void)ws_size; (void)out_size;
    hipFuncSetAttribute(reinterpret_cast<const void*>(lstm_ae),
                        hipFuncAttributeMaxDynamicSharedMemorySize, SMEM_BYTES);
    const float* xi = (const float*)d_in[0];
    const float* w1ih = (const float*)d_in[1];
    const float* w1hh = (const float*)d_in[2];
    const float* b1i = (const float*)d_in[3];
    const float* b1h = (const float*)d_in[4];
    const float* w2ih = (const float*)d_in[5];
    const float* w2hh = (const float*)d_in[6];
    const float* b2i = (const float*)d_in[7];
    const float* b2h = (const float*)d_in[8];
    const float* w3ih = (const float*)d_in[9];
    const float* w3hh = (const float*)d_in[10];
    const float* b3i = (const float*)d_in[11];
    const float* b3h = (const float*)d_in[12];
    const float* w4ih = (const float*)d_in[13];
    const float* w4hh = (const float*)d_in[14];
    const float* b4i = (const float*)d_in[15];
    const float* b4h = (const float*)d_in[16];
    float* out = (float*)d_out;

    lstm_ae<<<dim3(BATCH / BPB), dim3(BLOCKT), SMEM_BYTES, stream>>>(
        xi, w1ih, w1hh, b1i, b1h, w2ih, w2hh, b2i, b2h,
        w3ih, w3hh, b3i, b3h, w4ih, w4hh, b4i, b4h, out);
}